// Round 1
// baseline (23395.743 us; speedup 1.0000x reference)
//
#include <hip/hip_runtime.h>

#define NN 50000
#define NE 1600000
#define F 32
#define T 4
#define FT 8
#define ED 16
#define NLAYERS 5

// ---- ordered-uint mapping for float atomic max (monotone, handles negatives) ----
__device__ __forceinline__ unsigned ford(float f) {
    unsigned u = __float_as_uint(f);
    return (u & 0x80000000u) ? ~u : (u | 0x80000000u);
}
__device__ __forceinline__ float funord(unsigned u) {
    return (u & 0x80000000u) ? __uint_as_float(u ^ 0x80000000u) : __uint_as_float(~u);
}
#define ORD_NEG_INF 0x007FFFFFu   // ford(-inf)

// Kernel A: per (node, channel): a = preW_xi . xt, b = preW_xj . xt ; init agg buffers
__global__ void node_pre(const float* __restrict__ xin,
                         const float* __restrict__ preW,   // [T,24,8] this layer
                         float* __restrict__ a, float* __restrict__ b,
                         float* __restrict__ ssum, unsigned* __restrict__ mxu,
                         int* __restrict__ cnt) {
    int idx = blockIdx.x * 256 + threadIdx.x;
    if (idx >= NN * F) return;
    int n = idx >> 5, ch = idx & 31;
    int t = ch >> 3, f = ch & 7;
    const float* xrow = xin + n * F + t * FT;
    const float* wA = preW + (t * 24) * 8 + f;       // rows 0..7  (xi)
    const float* wB = preW + (t * 24 + 8) * 8 + f;   // rows 8..15 (xj)
    float av = 0.f, bv = 0.f;
#pragma unroll
    for (int k = 0; k < 8; k++) {
        float xv = xrow[k];
        av += xv * wA[k * 8];
        bv += xv * wB[k * 8];
    }
    a[idx] = av;
    b[idx] = bv;
    ssum[idx] = 0.f;
    mxu[idx] = ORD_NEG_INF;
    if (ch == 0) cnt[n] = 0;
}

// Kernel B: per edge: ee = edge encoder; h = a[dst] + b[src] + preW_ee.ee + preb;
// scatter sum/max/count via atomics.
__global__ void edge_kernel(const int* __restrict__ ei,      // [2,E]
                            const float* __restrict__ eattr, // [E,16]
                            const float* __restrict__ eW,    // [16,8]
                            const float* __restrict__ ebias, // [8]
                            const float* __restrict__ preW,  // [T,24,8]
                            const float* __restrict__ preb,  // [T,8]
                            const float* __restrict__ a, const float* __restrict__ b,
                            float* __restrict__ ssum, unsigned* __restrict__ mxu,
                            int* __restrict__ cnt) {
    int e = blockIdx.x * 256 + threadIdx.x;
    if (e >= NE) return;
    int src = ei[e];
    int dst = ei[NE + e];

    float ea[16];
    const float4* eap = (const float4*)(eattr + (size_t)e * ED);
#pragma unroll
    for (int q = 0; q < 4; q++) {
        float4 v = eap[q];
        ea[q * 4 + 0] = v.x; ea[q * 4 + 1] = v.y;
        ea[q * 4 + 2] = v.z; ea[q * 4 + 3] = v.w;
    }
    float ee[8];
#pragma unroll
    for (int j = 0; j < 8; j++) ee[j] = ebias[j];
#pragma unroll
    for (int k = 0; k < 16; k++) {
        float av = ea[k];
#pragma unroll
        for (int j = 0; j < 8; j++) ee[j] += av * eW[k * 8 + j];
    }

    const float* arow = a + (size_t)dst * F;
    const float* brow = b + (size_t)src * F;
    float* srow = ssum + (size_t)dst * F;
    unsigned* mrow = mxu + (size_t)dst * F;

#pragma unroll
    for (int t = 0; t < T; t++) {
#pragma unroll
        for (int f = 0; f < 8; f++) {
            float c = preb[t * 8 + f];
#pragma unroll
            for (int j = 0; j < 8; j++) c += ee[j] * preW[(t * 24 + 16 + j) * 8 + f];
            float h = arow[t * 8 + f] + brow[t * 8 + f] + c;
            atomicAdd(&srow[t * 8 + f], h);
            atomicMax(&mrow[t * 8 + f], ford(h));
        }
    }
    atomicAdd(&cnt[dst], 1);
}

// Kernel C: per node: concat[xt, mean, sum, max] -> per-tower post-MLP -> lin -> relu
// 32 lanes per node, 8 nodes per 256-thread block.
__global__ void node_post(const float* __restrict__ xin,
                          const float* __restrict__ ssum, const unsigned* __restrict__ mxu,
                          const int* __restrict__ cnt,
                          const float* __restrict__ postW, // [T,32,8]
                          const float* __restrict__ postb, // [T,8]
                          const float* __restrict__ linW,  // [32,32]
                          const float* __restrict__ linb,  // [32]
                          float* __restrict__ xout) {
    __shared__ float cat[8][128];  // [node_local][group*32 + ch]
    __shared__ float um[8][32];
    int tid = threadIdx.x;
    int nl = tid >> 5, ch = tid & 31;
    int n = blockIdx.x * 8 + nl;
    int t = ch >> 3, f = ch & 7;

    float xv = 0.f, mean = 0.f, sv = 0.f, mv = 0.f;
    if (n < NN) {
        int idx = n * F + ch;
        xv = xin[idx];
        sv = ssum[idx];
        int c = cnt[n];
        mv = (c > 0) ? funord(mxu[idx]) : 0.f;
        mean = sv / fmaxf((float)c, 1.f);
    }
    cat[nl][0 * 32 + ch] = xv;
    cat[nl][1 * 32 + ch] = mean;
    cat[nl][2 * 32 + ch] = sv;
    cat[nl][3 * 32 + ch] = mv;
    __syncthreads();

    float u = postb[t * 8 + f];
#pragma unroll
    for (int k = 0; k < 32; k++) {
        int g = k >> 3, kk = k & 7;
        u += cat[nl][g * 32 + t * 8 + kk] * postW[(t * 32 + k) * 8 + f];
    }
    um[nl][ch] = u;
    __syncthreads();

    float y = linb[ch];
#pragma unroll
    for (int k = 0; k < 32; k++) y += um[nl][k] * linW[k * 32 + ch];
    y = fmaxf(y, 0.f);
    if (n < NN) xout[(size_t)n * F + ch] = y;
}

extern "C" void kernel_launch(void* const* d_in, const int* in_sizes, int n_in,
                              void* d_out, int out_size, void* d_ws, size_t ws_size,
                              hipStream_t stream) {
    const float* x      = (const float*)d_in[0];
    const int*   ei     = (const int*)d_in[1];
    const float* eattr  = (const float*)d_in[2];
    const float* edge_W = (const float*)d_in[3];
    const float* edge_b = (const float*)d_in[4];
    const float* pre_W  = (const float*)d_in[5];
    const float* pre_b  = (const float*)d_in[6];
    const float* post_W = (const float*)d_in[7];
    const float* post_b = (const float*)d_in[8];
    const float* lin_W  = (const float*)d_in[9];
    const float* lin_b  = (const float*)d_in[10];
    float* out = (float*)d_out;

    const size_t NC = (size_t)NN * F;
    float* ws   = (float*)d_ws;
    float* a    = ws;
    float* b    = a + NC;
    float* ssum = b + NC;
    unsigned* mxu = (unsigned*)(ssum + NC);
    int* cnt    = (int*)(mxu + NC);
    float* xb0  = (float*)(cnt + NN);
    float* xb1  = xb0 + NC;

    dim3 blk(256);
    int gA = (NN * F + 255) / 256;
    int gB = (NE + 255) / 256;
    int gC = (NN + 7) / 8;

    const float* xin = x;
    for (int l = 0; l < NLAYERS; l++) {
        const float* eW  = edge_W + (size_t)l * ED * FT;
        const float* eb  = edge_b + (size_t)l * FT;
        const float* pW  = pre_W  + (size_t)l * T * 24 * FT;
        const float* pb  = pre_b  + (size_t)l * T * FT;
        const float* poW = post_W + (size_t)l * T * 32 * FT;
        const float* pob = post_b + (size_t)l * T * FT;
        const float* lW  = lin_W  + (size_t)l * F * F;
        const float* lb  = lin_b  + (size_t)l * F;
        float* xout = (l == NLAYERS - 1) ? out : ((l & 1) ? xb1 : xb0);

        hipLaunchKernelGGL(node_pre, dim3(gA), blk, 0, stream,
                           xin, pW, a, b, ssum, mxu, cnt);
        hipLaunchKernelGGL(edge_kernel, dim3(gB), blk, 0, stream,
                           ei, eattr, eW, eb, pW, pb, a, b, ssum, mxu, cnt);
        hipLaunchKernelGGL(node_post, dim3(gC), blk, 0, stream,
                           xin, ssum, mxu, cnt, poW, pob, lW, lb, xout);
        xin = xout;
    }
}

// Round 2
// 1103.139 us; speedup vs baseline: 21.2083x; 21.2083x over previous
//
#include <hip/hip_runtime.h>

#define NN 50000
#define NE 1600000
#define F 32
#define T 4
#define FT 8
#define ED 16
#define NLAYERS 5

// ---------------- CSR build (once per call; edge_index constant across layers) ----

__global__ void zero_cnt(int* __restrict__ cnt) {
    int i = blockIdx.x * 256 + threadIdx.x;
    if (i < NN) cnt[i] = 0;
}

__global__ void count_kernel(const int* __restrict__ ei, int* __restrict__ cnt) {
    int e = blockIdx.x * 256 + threadIdx.x;
    if (e >= NE) return;
    atomicAdd(&cnt[ei[NE + e]], 1);
}

// one-block exclusive scan over cnt[NN] -> row_ptr, cursor (1024 threads)
__global__ void scan_kernel(const int* __restrict__ cnt, int* __restrict__ row_ptr,
                            int* __restrict__ cursor) {
    __shared__ int wsum[16];
    __shared__ int carry_s;
    int tid = threadIdx.x;
    int lane = tid & 63, wid = tid >> 6;
    if (tid == 0) carry_s = 0;
    __syncthreads();
    for (int base = 0; base < NN; base += 1024) {
        int i = base + tid;
        int v = (i < NN) ? cnt[i] : 0;
        int s = v;
#pragma unroll
        for (int off = 1; off < 64; off <<= 1) {
            int tt = __shfl_up(s, off, 64);
            if (lane >= off) s += tt;
        }
        __syncthreads();                 // wsum/carry from prev tile fully consumed
        if (lane == 63) wsum[wid] = s;
        __syncthreads();
        if (wid == 0 && lane < 16) {
            int w = wsum[lane];
            int ws = w;
#pragma unroll
            for (int off = 1; off < 16; off <<= 1) {
                int tt = __shfl_up(ws, off, 16);
                if (lane >= off) ws += tt;
            }
            wsum[lane] = ws - w;         // exclusive wave offsets
        }
        __syncthreads();
        int excl = carry_s + wsum[wid] + s - v;
        if (i < NN) { row_ptr[i] = excl; cursor[i] = excl; }
        __syncthreads();
        if (tid == 1023) carry_s += wsum[15] + s;
    }
}

__global__ void scatter_kernel(const int* __restrict__ ei, int* __restrict__ cursor,
                               int* __restrict__ eid_s, int* __restrict__ src_s) {
    int e = blockIdx.x * 256 + threadIdx.x;
    if (e >= NE) return;
    int dst = ei[NE + e];
    int p = atomicAdd(&cursor[dst], 1);
    eid_s[p] = e;
    src_s[p] = ei[e];
}

// ---------------- per-layer kernels ----------------

// Wc[k][ch] = sum_j eW[k][j] * preW_ee[t][j][f]   (16x32)
__global__ void wc_kernel(const float* __restrict__ eW, const float* __restrict__ preW,
                          float* __restrict__ Wc) {
    int idx = threadIdx.x;
    if (idx >= 512) return;
    int k = idx >> 5, ch = idx & 31;
    int t = ch >> 3, f = ch & 7;
    float sum = 0.f;
#pragma unroll
    for (int j = 0; j < 8; j++) sum += eW[k * 8 + j] * preW[(t * 24 + 16 + j) * 8 + f];
    Wc[k * 32 + ch] = sum;
}

// a[n][ch] = preW_xi . xt + preb + (eb . preW_ee) ;  b[n][ch] = preW_xj . xt
__global__ void node_pre(const float* __restrict__ xin,
                         const float* __restrict__ preW, const float* __restrict__ preb,
                         const float* __restrict__ ebias,
                         float* __restrict__ a, float* __restrict__ b) {
    int idx = blockIdx.x * 256 + threadIdx.x;
    if (idx >= NN * F) return;
    int n = idx >> 5, ch = idx & 31;
    int t = ch >> 3, f = ch & 7;
    const float* xrow = xin + n * F + t * FT;
    const float* wA = preW + (t * 24) * 8 + f;
    const float* wB = preW + (t * 24 + 8) * 8 + f;
    float av = preb[t * 8 + f];
#pragma unroll
    for (int j = 0; j < 8; j++) av += ebias[j] * preW[(t * 24 + 16 + j) * 8 + f];
    float bv = 0.f;
#pragma unroll
    for (int k = 0; k < 8; k++) {
        float xv = xrow[k];
        av += xv * wA[k * 8];
        bv += xv * wB[k * 8];
    }
    a[idx] = av;
    b[idx] = bv;
}

// one wave per dst node; 32 lanes = channels, 2 halves = 2 edges per iteration.
__global__ __launch_bounds__(256) void gather_post(
        const float* __restrict__ xin, const float* __restrict__ a,
        const float* __restrict__ b, const float* __restrict__ eattr,
        const int* __restrict__ row_ptr, const int* __restrict__ cnt,
        const int* __restrict__ eid_s, const int* __restrict__ src_s,
        const float* __restrict__ Wc,
        const float* __restrict__ postW, const float* __restrict__ postb,
        const float* __restrict__ linW, const float* __restrict__ linb,
        float* __restrict__ xout) {
    __shared__ float cat[4][128];
    __shared__ float um[4][32];
    int tid = threadIdx.x;
    int wv = tid >> 6;
    int lane = tid & 63;
    int ch = lane & 31, half = lane >> 5;
    int n = blockIdx.x * 4 + wv;           // NN=50000 divisible by 4 -> no bounds check
    int t = ch >> 3, f = ch & 7;

    float wc[16];
#pragma unroll
    for (int k = 0; k < 16; k++) wc[k] = Wc[k * 32 + ch];
    float a_val = a[n * F + ch];
    int rs = row_ptr[n], deg = cnt[n];

    float S = 0.f, M = -3.4e38f;
    for (int i = rs + half; i < rs + deg; i += 2) {
        int eid = eid_s[i];
        int s = src_s[i];
        const float4* ep = (const float4*)(eattr + (size_t)eid * ED);
        float4 e0 = ep[0], e1 = ep[1], e2 = ep[2], e3 = ep[3];
        float bv = b[s * F + ch];
        float c = e0.x * wc[0] + e0.y * wc[1] + e0.z * wc[2] + e0.w * wc[3]
                + e1.x * wc[4] + e1.y * wc[5] + e1.z * wc[6] + e1.w * wc[7]
                + e2.x * wc[8] + e2.y * wc[9] + e2.z * wc[10] + e2.w * wc[11]
                + e3.x * wc[12] + e3.y * wc[13] + e3.z * wc[14] + e3.w * wc[15];
        float h = bv + c;
        S += h;
        M = fmaxf(M, h);
    }
    S += __shfl_xor(S, 32, 64);
    M = fmaxf(M, __shfl_xor(M, 32, 64));

    float xv = xin[n * F + ch];
    float sum_h, mean_h, max_h;
    if (deg > 0) {
        sum_h = S + (float)deg * a_val;
        mean_h = sum_h / (float)deg;
        max_h = M + a_val;
    } else {
        sum_h = 0.f; mean_h = 0.f; max_h = 0.f;
    }
    if (half == 0) {
        cat[wv][0 * 32 + ch] = xv;
        cat[wv][1 * 32 + ch] = mean_h;
        cat[wv][2 * 32 + ch] = sum_h;
        cat[wv][3 * 32 + ch] = max_h;
    }
    __syncthreads();
    if (half == 0) {
        float u = postb[t * 8 + f];
#pragma unroll
        for (int k = 0; k < 32; k++) {
            int g = k >> 3, kk = k & 7;
            u += cat[wv][g * 32 + t * 8 + kk] * postW[(t * 32 + k) * 8 + f];
        }
        um[wv][ch] = u;
    }
    __syncthreads();
    if (half == 0) {
        float y = linb[ch];
#pragma unroll
        for (int k = 0; k < 32; k++) y += um[wv][k] * linW[k * 32 + ch];
        xout[(size_t)n * F + ch] = fmaxf(y, 0.f);
    }
}

// ---------------- launch ----------------

extern "C" void kernel_launch(void* const* d_in, const int* in_sizes, int n_in,
                              void* d_out, int out_size, void* d_ws, size_t ws_size,
                              hipStream_t stream) {
    const float* x      = (const float*)d_in[0];
    const int*   ei     = (const int*)d_in[1];
    const float* eattr  = (const float*)d_in[2];
    const float* edge_W = (const float*)d_in[3];
    const float* edge_b = (const float*)d_in[4];
    const float* pre_W  = (const float*)d_in[5];
    const float* pre_b  = (const float*)d_in[6];
    const float* post_W = (const float*)d_in[7];
    const float* post_b = (const float*)d_in[8];
    const float* lin_W  = (const float*)d_in[9];
    const float* lin_b  = (const float*)d_in[10];
    float* out = (float*)d_out;

    const size_t NC = (size_t)NN * F;
    char* p = (char*)d_ws;
    int* cnt     = (int*)p;            p += sizeof(int) * NN;
    int* row_ptr = (int*)p;            p += sizeof(int) * NN;
    int* cursor  = (int*)p;            p += sizeof(int) * NN;
    int* eid_s   = (int*)p;            p += sizeof(int) * NE;
    int* src_s   = (int*)p;            p += sizeof(int) * NE;
    float* a     = (float*)p;          p += sizeof(float) * NC;
    float* b     = (float*)p;          p += sizeof(float) * NC;
    float* Wc    = (float*)p;          p += sizeof(float) * 16 * 32;
    float* xb0   = (float*)p;          p += sizeof(float) * NC;
    float* xb1   = (float*)p;          p += sizeof(float) * NC;

    dim3 blk(256);
    int gN  = (NN + 255) / 256;
    int gE  = (NE + 255) / 256;
    int gNC = (NN * F + 255) / 256;
    int gG  = NN / 4;

    // CSR build (once; reused by all 5 layers)
    hipLaunchKernelGGL(zero_cnt,      dim3(gN), blk, 0, stream, cnt);
    hipLaunchKernelGGL(count_kernel,  dim3(gE), blk, 0, stream, ei, cnt);
    hipLaunchKernelGGL(scan_kernel,   dim3(1), dim3(1024), 0, stream, cnt, row_ptr, cursor);
    hipLaunchKernelGGL(scatter_kernel,dim3(gE), blk, 0, stream, ei, cursor, eid_s, src_s);

    const float* xin = x;
    for (int l = 0; l < NLAYERS; l++) {
        const float* eW  = edge_W + (size_t)l * ED * FT;
        const float* eb  = edge_b + (size_t)l * FT;
        const float* pW  = pre_W  + (size_t)l * T * 24 * FT;
        const float* pb  = pre_b  + (size_t)l * T * FT;
        const float* poW = post_W + (size_t)l * T * 32 * FT;
        const float* pob = post_b + (size_t)l * T * FT;
        const float* lW  = lin_W  + (size_t)l * F * F;
        const float* lb  = lin_b  + (size_t)l * F;
        float* xout = (l == NLAYERS - 1) ? out : ((l & 1) ? xb1 : xb0);

        hipLaunchKernelGGL(wc_kernel, dim3(1), dim3(512), 0, stream, eW, pW, Wc);
        hipLaunchKernelGGL(node_pre,  dim3(gNC), blk, 0, stream, xin, pW, pb, eb, a, b);
        hipLaunchKernelGGL(gather_post, dim3(gG), blk, 0, stream,
                           xin, a, b, eattr, row_ptr, cnt, eid_s, src_s, Wc,
                           poW, pob, lW, lb, xout);
        xin = xout;
    }
}